// Round 3
// baseline (1766.736 us; speedup 1.0000x reference)
//
#include <hip/hip_runtime.h>
#include <stdint.h>

#define BB 128
#define SS 2048
#define TT 128
#define NSEG 32
#define SEGK 64

typedef float f32x4 __attribute__((ext_vector_type(4)));

// raw barrier: drain LDS ops only (NOT vmcnt -> prefetch loads stay in flight)
#define BAR() asm volatile("s_waitcnt lgkmcnt(0)\n\ts_barrier" ::: "memory")

// pin a value into VGPRs: asm-defined values cannot be rematerialized from LDS
#define PIN(x) asm volatile("" : "+v"(x))

// ---------------- main kernel: 256 blocks. role 0 (blocks 0..127) = viterbi,
// role 1 (blocks 128..255) = forward(logZ) + numerator. 256 threads: j=tid>>1,
// h=tid&1 owns i-half [64h,64h+64). ----------------
__attribute__((amdgpu_flat_work_group_size(256, 256)))
__attribute__((amdgpu_waves_per_eu(1, 1)))
__global__ void crf_mainX(const float* __restrict__ logit,
                          const int* __restrict__ seq_lens,
                          const float* __restrict__ trans,
                          const float* __restrict__ startT,
                          const float* __restrict__ endT,
                          const int* __restrict__ target,
                          uint8_t* __restrict__ histG,
                          float* __restrict__ scr_logZ,
                          int* __restrict__ scr_last,
                          float* __restrict__ scr_num)
{
    extern __shared__ float smem[];
    float* transLDS = smem;                       // 16384 floats
    float* vecLDS   = smem + 16384;               // 2*128 (score / aexp)
    float* ringLDS  = smem + 16384 + 256;         // 4 (fwd shift ring)
    float* redLDS   = smem + 16384 + 260;         // 8
    int*   redILDS  = (int*)(smem + 16384 + 268); // 4
    float* sumLDS   = smem + 16384 + 272;         // 4

    const int bid = blockIdx.x;
    const int role = bid >> 7;
    const int b = bid & (BB - 1);
    const int tid = threadIdx.x;
    const int j = tid >> 1;
    const int h = tid & 1;
    const int ibase0 = h << 6;
    const int L = seq_lens[b];
    const size_t lbase = (size_t)b * (SS * TT);

    // stage transitions into LDS (row-major)
    {
        const float4* g = (const float4*)trans;
        float4* l = (float4*)transLDS;
        for (int k = tid; k < (TT * TT) / 4; k += 256) l[k] = g[k];
    }
    __syncthreads();

    // depth-2 logit prefetch registers (row t+0 consumed from e1)
    float e1 = 0.f, e2 = 0.f;
    if (L > 1) e1 = logit[lbase + TT + j];
    e2 = (L > 2) ? logit[lbase + 2 * (size_t)TT + j] : e1;

    if (role == 0) {
        // =================== VITERBI ===================
        f32x4 tC[16];  // trans[i][j] for my i-half — pinned into VGPRs
#pragma unroll
        for (int c = 0; c < 16; ++c) {
            tC[c].x = transLDS[(ibase0 + c * 4 + 0) * TT + j];
            tC[c].y = transLDS[(ibase0 + c * 4 + 1) * TT + j];
            tC[c].z = transLDS[(ibase0 + c * 4 + 2) * TT + j];
            tC[c].w = transLDS[(ibase0 + c * 4 + 3) * TT + j];
            PIN(tC[c]);
        }
        const float a0 = startT[j] + logit[lbase + j];
        if (h == 0) vecLDS[j] = a0;
        __syncthreads();

        for (int t = 1; t < L; ++t) {
            const int cur = (t - 1) & 1, nxt = t & 1;
            const float e = e1; e1 = e2;
            const int tn = (t + 2 < L) ? (t + 2) : (L - 1);
            e2 = logit[lbase + (size_t)tn * TT + j];

            // pass 1: P_i = s_i + t_ij (NO +e: max_i((s+t)+e) == (max_i(s+t))+e exactly)
            const f32x4* sq = (const f32x4*)(vecLDS + cur * TT + ibase0);
            float cm[8];
#pragma unroll
            for (int c = 0; c < 8; ++c) {
                f32x4 sa = sq[2 * c], sb = sq[2 * c + 1];
                f32x4 ta = tC[2 * c], tb = tC[2 * c + 1];
                float p0 = sa.x + ta.x, p1 = sa.y + ta.y;
                float p2 = sa.z + ta.z, p3 = sa.w + ta.w;
                float p4 = sb.x + tb.x, p5 = sb.y + tb.y;
                float p6 = sb.z + tb.z, p7 = sb.w + tb.w;
                float A  = fmaxf(fmaxf(p0, p1), p2);
                float Bm = fmaxf(fmaxf(p3, p4), p5);
                float C  = fmaxf(p6, p7);
                cm[c] = fmaxf(fmaxf(A, Bm), C);
            }
            float M = fmaxf(fmaxf(fmaxf(cm[0], cm[1]), cm[2]),
                            fmaxf(fmaxf(cm[3], cm[4]),
                                  fmaxf(cm[5], fmaxf(cm[6], cm[7]))));
            const float Mo = __shfl_xor(M, 1);
            const float Mall = fmaxf(M, Mo);
            const float v = Mall + e;   // exact reference max value

            // first chunk (in my half) whose max could round-equal v after +e
            int cwin = -1;
#pragma unroll
            for (int c = 7; c >= 0; --c) cwin = ((cm[c] + e) == v) ? c : cwin;

            int idx = 0x7fffffff;
            if (cwin >= 0) {
                const int basei = ibase0 + cwin * 8;
                const float* tr = transLDS + (size_t)basei * TT + j;
                const f32x4* sr = (const f32x4*)(vecLDS + cur * TT + basei);
                f32x4 ra = sr[0], rb = sr[1];
                float q0 = (ra.x + tr[0 * TT]) + e;
                float q1 = (ra.y + tr[1 * TT]) + e;
                float q2 = (ra.z + tr[2 * TT]) + e;
                float q3 = (ra.w + tr[3 * TT]) + e;
                float q4 = (rb.x + tr[4 * TT]) + e;
                float q5 = (rb.y + tr[5 * TT]) + e;
                float q6 = (rb.z + tr[6 * TT]) + e;
                float q7 = (rb.w + tr[7 * TT]) + e;
                idx = (q7 == v) ? basei + 7 : idx;
                idx = (q6 == v) ? basei + 6 : idx;
                idx = (q5 == v) ? basei + 5 : idx;
                idx = (q4 == v) ? basei + 4 : idx;
                idx = (q3 == v) ? basei + 3 : idx;
                idx = (q2 == v) ? basei + 2 : idx;
                idx = (q1 == v) ? basei + 1 : idx;
                idx = (q0 == v) ? basei + 0 : idx;
            }
            const int oidx = __shfl_xor(idx, 1);
            idx = (oidx < idx) ? oidx : idx;  // first-index across halves

            if (h == 0) {
                vecLDS[nxt * TT + j] = v;
                histG[(size_t)b * (SS * TT) + (size_t)t * TT + j] = (uint8_t)idx;
            }
            BAR();
        }

        // ---- last_tag = argmax_j(score + end), first-index ----
        const int fin = (L - 1) & 1;
        if (tid < 128) {
            float lv = vecLDS[fin * TT + tid] + endT[tid];
            int li = tid;
#pragma unroll
            for (int off = 1; off < 64; off <<= 1) {
                float ov = __shfl_xor(lv, off);
                int oi = __shfl_xor(li, off);
                if (ov > lv || (ov == lv && oi < li)) { lv = ov; li = oi; }
            }
            if ((tid & 63) == 0) { redLDS[tid >> 6] = lv; redILDS[tid >> 6] = li; }
        }
        __syncthreads();
        if (tid == 0) {
            int lt = (redLDS[1] > redLDS[0] ||
                      (redLDS[1] == redLDS[0] && redILDS[1] < redILDS[0]))
                     ? redILDS[1] : redILDS[0];
            scr_last[b] = lt;
        }
        // ---- identity fill of hist rows [L, SS) ----
        uint8_t* hb = histG + (size_t)b * (SS * TT);
        const int colq = (tid & 7) * 16;
        const uint32_t w0 = 0x03020100u + 0x01010101u * (uint32_t)colq;
        const uint4 pat = make_uint4(w0, w0 + 0x04040404u, w0 + 0x08080808u, w0 + 0x0C0C0C0Cu);
        for (int t0 = L; t0 < SS; t0 += 32) {
            int t = t0 + (tid >> 3);
            if (t < SS) *(uint4*)(hb + (size_t)t * TT + colq) = pat;
        }
    } else {
        // =================== FORWARD (logZ) ===================
        f32x4 tE[16];  // exp(trans[i][j]) — pinned into VGPRs
#pragma unroll
        for (int c = 0; c < 16; ++c) {
            tE[c].x = __expf(transLDS[(ibase0 + c * 4 + 0) * TT + j]);
            tE[c].y = __expf(transLDS[(ibase0 + c * 4 + 1) * TT + j]);
            tE[c].z = __expf(transLDS[(ibase0 + c * 4 + 2) * TT + j]);
            tE[c].w = __expf(transLDS[(ibase0 + c * 4 + 3) * TT + j]);
            PIN(tE[c]);
        }
        const float a0 = startT[j] + logit[lbase + j];
        const float R0 = startT[0] + logit[lbase + 0];  // alpha0[0], uniform
        float alpha = a0;
        if (h == 0) vecLDS[j] = __expf(a0 - R0);
        if (tid < 4) ringLDS[tid] = R0;
        __syncthreads();

        for (int t = 1; t < L; ++t) {
            const int cur = (t - 1) & 1, nxt = t & 1;
            const float Rcons = ringLDS[(t - 3) & 3];  // shift used by aexp[cur]
            const float Rpub  = ringLDS[(t - 2) & 3];  // shift for publishing aexp[nxt]
            const float e = e1; e1 = e2;
            const int tn = (t + 2 < L) ? (t + 2) : (L - 1);
            e2 = logit[lbase + (size_t)tn * TT + j];

            const f32x4* aq = (const f32x4*)(vecLDS + cur * TT + ibase0);
            float s0 = 0.f, s1 = 0.f, s2 = 0.f, s3 = 0.f;
#pragma unroll
            for (int c = 0; c < 16; ++c) {
                f32x4 av = aq[c]; f32x4 tv = tE[c];
                s0 = fmaf(av.x, tv.x, s0);
                s1 = fmaf(av.y, tv.y, s1);
                s2 = fmaf(av.z, tv.z, s2);
                s3 = fmaf(av.w, tv.w, s3);
            }
            float Ssum = (s0 + s1) + (s2 + s3);
            Ssum += __shfl_xor(Ssum, 1);
            alpha = e + Rcons + __logf(Ssum);
            const float p = __expf(alpha - Rpub);
            if (h == 0) vecLDS[nxt * TT + j] = p;
            if (tid == 0) ringLDS[t & 3] = alpha;  // slot t&3: no reader this step
            BAR();
        }

        // ---- logZ epilogue (exact max this time) ----
        const float fval = alpha + endT[j];
        float tmx = fval;
#pragma unroll
        for (int off = 1; off < 64; off <<= 1) tmx = fmaxf(tmx, __shfl_xor(tmx, off));
        if ((tid & 63) == 0) redLDS[4 + (tid >> 6)] = tmx;
        __syncthreads();
        const float gm = fmaxf(fmaxf(redLDS[4], redLDS[5]), fmaxf(redLDS[6], redLDS[7]));
        float se = (h == 0) ? __expf(fval - gm) : 0.f;
#pragma unroll
        for (int off = 1; off < 64; off <<= 1) se += __shfl_xor(se, off);
        if ((tid & 63) == 0) sumLDS[tid >> 6] = se;
        __syncthreads();
        if (tid == 0)
            scr_logZ[b] = gm + __logf(sumLDS[0] + sumLDS[1] + sumLDS[2] + sumLDS[3]);
        __syncthreads();

        // ---- numerator (gold path score) ----
        float acc = 0.f;
        for (int t = tid; t < L; t += 256) {
            int tg = target[b * SS + t];
            acc += logit[((size_t)b * SS + t) * TT + tg];
            if (t >= 1) acc += trans[target[b * SS + t - 1] * TT + tg];
        }
#pragma unroll
        for (int off = 1; off < 64; off <<= 1) acc += __shfl_xor(acc, off);
        if ((tid & 63) == 0) sumLDS[tid >> 6] = acc;
        __syncthreads();
        if (tid == 0) {
            float tot = sumLDS[0] + sumLDS[1] + sumLDS[2] + sumLDS[3];
            tot += startT[target[b * SS]] + endT[target[b * SS + L - 1]];
            scr_num[b] = tot;
        }
    }
}

// ---------------- phase 2: per-segment parallel backtrace of all 128 end-tags ----------------
__global__ void crf_btseg(uint8_t* __restrict__ histG)
{
    const int c = blockIdx.x;    // segment 0..31
    const int b = blockIdx.y;    // batch
    const int tid = threadIdx.x; // 128
    __shared__ __align__(16) uint8_t hl[SEGK * TT];

    const int lo = (c == 0) ? 1 : c * SEGK;
    const int nr = (c == 0) ? 63 : 64;
    const uint8_t* src = histG + (size_t)b * (SS * TT) + (size_t)lo * TT;
    for (int k = tid; k < (nr * TT) / 16; k += 128)
        ((uint4*)hl)[k] = ((const uint4*)src)[k];
    __syncthreads();

    int tau = tid;
    uint32_t w[16];
#pragma unroll
    for (int q = 0; q < 16; ++q) w[q] = 0u;
    if (c == 0) {
#pragma unroll
        for (int r = 62; r >= 0; --r) {
            tau = hl[r * TT + tau];
            w[r >> 2] |= ((uint32_t)tau) << ((r & 3) * 8);
        }
    } else {
#pragma unroll
        for (int r = 63; r >= 0; --r) {
            tau = hl[r * TT + tau];
            w[r >> 2] |= ((uint32_t)tau) << ((r & 3) * 8);
        }
    }
    uint4* dst = (uint4*)(histG + (size_t)b * (SS * TT) + (size_t)c * 8192 + (size_t)tid * 64);
    dst[0] = make_uint4(w[0], w[1], w[2], w[3]);
    dst[1] = make_uint4(w[4], w[5], w[6], w[7]);
    dst[2] = make_uint4(w[8], w[9], w[10], w[11]);
    dst[3] = make_uint4(w[12], w[13], w[14], w[15]);
}

// ---------------- phase 3: serial chain over 32 segment maps per batch ----------------
__global__ void crf_btchain(const uint8_t* __restrict__ histG,
                            const int* __restrict__ scr_last,
                            int* __restrict__ scr_bt,
                            float* __restrict__ out_pred)
{
    const int b = threadIdx.x;
    if (b >= BB) return;
    int tau = scr_last[b];
    out_pred[(size_t)b * SS + (SS - 1)] = (float)tau;
    for (int c = NSEG - 1; c >= 0; --c) {
        scr_bt[b * NSEG + c] = tau;
        tau = histG[(size_t)b * (SS * TT) + (size_t)c * 8192 + (size_t)tau * 64];
    }
}

// ---------------- phase 4: parallel fill of pred from chosen paths ----------------
__global__ void crf_btfill(const uint8_t* __restrict__ histG,
                           const int* __restrict__ scr_bt,
                           float* __restrict__ out_pred)
{
    const int c = blockIdx.x;
    const int b = blockIdx.y;
    const int s = threadIdx.x;   // 64
    if (c == 0 && s > 62) return;
    const int js = scr_bt[b * NSEG + c];
    uint8_t v = histG[(size_t)b * (SS * TT) + (size_t)c * 8192 + (size_t)js * 64 + s];
    const int pos = (c == 0) ? s : (c * SEGK - 1 + s);
    out_pred[(size_t)b * SS + pos] = (float)v;
}

// ---------------- loss = mean(logZ - num) ----------------
__global__ void crf_loss(const float* __restrict__ scr_logZ, const float* __restrict__ scr_num,
                         float* __restrict__ out)
{
    const int tid = threadIdx.x; // 128
    __shared__ float p2[2];
    float v = (tid < BB) ? (scr_logZ[tid] - scr_num[tid]) : 0.0f;
#pragma unroll
    for (int off = 1; off < 64; off <<= 1) v += __shfl_xor(v, off);
    if ((tid & 63) == 0) p2[tid >> 6] = v;
    __syncthreads();
    if (tid == 0) out[0] = (p2[0] + p2[1]) / (float)BB;
}

// ---------------- log_probs: swap + log_softmax, one wave per row ----------------
__global__ void crf_logprobs(const float* __restrict__ logit,
                             const float* __restrict__ predF,
                             float* __restrict__ outLP)
{
    const int wid = threadIdx.x >> 6;
    const int lane = threadIdx.x & 63;
    const size_t row = (size_t)blockIdx.x * 4 + wid;
    const float2* rp = (const float2*)(logit + row * TT);
    float2 v = rp[lane];
    const int pred = (int)predF[row];

    float mv; int mi;
    if (v.y > v.x) { mv = v.y; mi = lane * 2 + 1; }
    else           { mv = v.x; mi = lane * 2; }
#pragma unroll
    for (int off = 1; off < 64; off <<= 1) {
        float ov = __shfl_xor(mv, off);
        int oi = __shfl_xor(mi, off);
        if (ov > mv || (ov == mv && oi < mi)) { mv = ov; mi = oi; }
    }
    float se = __expf(v.x - mv) + __expf(v.y - mv);
#pragma unroll
    for (int off = 1; off < 64; off <<= 1) se += __shfl_xor(se, off);
    const float lse = __logf(se);

    float px = __shfl(v.x, pred >> 1);
    float py = __shfl(v.y, pred >> 1);
    float vp = (pred & 1) ? py : px;

    float ox = (lane * 2 == pred) ? mv : ((lane * 2 == mi) ? vp : v.x);
    float oy = (lane * 2 + 1 == pred) ? mv : ((lane * 2 + 1 == mi) ? vp : v.y);
    float* op = outLP + row * TT + lane * 2;
    op[0] = (ox - mv) - lse;
    op[1] = (oy - mv) - lse;
}

extern "C" void kernel_launch(void* const* d_in, const int* in_sizes, int n_in,
                              void* d_out, int out_size, void* d_ws, size_t ws_size,
                              hipStream_t stream)
{
    const float* logit    = (const float*)d_in[0];
    const int*   target   = (const int*)d_in[1];
    const int*   seq_lens = (const int*)d_in[2];
    const float* trans    = (const float*)d_in[3];
    const float* startT   = (const float*)d_in[4];
    const float* endT     = (const float*)d_in[5];

    float* out      = (float*)d_out;
    float* out_pred = out + 1;
    float* outLP    = out + 1 + (size_t)BB * SS;                 // 262145
    uint8_t* histG  = (uint8_t*)(out + 262148);                  // 16B-aligned, 33.5MB
    // small scratch at tail of log_probs region (overwritten last by crf_logprobs)
    float* scr      = out + ((size_t)1 + (size_t)BB * SS + (size_t)BB * SS * TT - 4480);
    float* scr_logZ = scr;                // 128
    float* scr_num  = scr + 128;          // 128
    int*   scr_last = (int*)(scr + 256);  // 128
    int*   scr_bt   = (int*)(scr + 384);  // 128*32

    const int dynLDS = (16384 + 288) * 4;  // ~66.7KB
    hipFuncSetAttribute((const void*)crf_mainX,
                        hipFuncAttributeMaxDynamicSharedMemorySize, dynLDS);

    crf_mainX<<<2 * BB, 256, dynLDS, stream>>>(logit, seq_lens, trans, startT, endT,
                                               target, histG, scr_logZ, scr_last, scr_num);
    crf_btseg<<<dim3(NSEG, BB), 128, 0, stream>>>(histG);
    crf_btchain<<<1, 128, 0, stream>>>(histG, scr_last, scr_bt, out_pred);
    crf_btfill<<<dim3(NSEG, BB), 64, 0, stream>>>(histG, scr_bt, out_pred);
    crf_loss<<<1, 128, 0, stream>>>(scr_logZ, scr_num, out);
    crf_logprobs<<<(BB * SS) / 4, 256, 0, stream>>>(logit, out_pred, outLP);
}

// Round 4
// 1590.930 us; speedup vs baseline: 1.1105x; 1.1105x over previous
//
#include <hip/hip_runtime.h>
#include <stdint.h>

#define BB 128
#define SS 2048
#define TT 128
#define NSEG 32
#define SEGK 64

// padded layouts (bank-conflict-free)
#define TRP 129              // trans row stride (129 % 32 == 1)
#define VSTRIDE 136          // state buffer stride (16B aligned)
#define H1OFF 68             // half-1 offset (68 % 32 == 4 -> disjoint banks vs half-0)

typedef float f32x4 __attribute__((ext_vector_type(4)));

// raw barrier: drain LDS ops only (NOT vmcnt -> prefetch loads stay in flight)
#define BAR() asm volatile("s_waitcnt lgkmcnt(0)\n\ts_barrier" ::: "memory")

// pin a value into VGPRs
#define PIN(x) asm volatile("" : "+v"(x))

// lane^1 swap via DPP quad_perm [1,0,3,2] — no LDS, ~4cyc
__device__ __forceinline__ float dpp_swap1_f(float x) {
    int i = __float_as_int(x);
    i = __builtin_amdgcn_update_dpp(0, i, 0xB1, 0xF, 0xF, true);
    return __int_as_float(i);
}
__device__ __forceinline__ int dpp_swap1_i(int x) {
    return __builtin_amdgcn_update_dpp(0, x, 0xB1, 0xF, 0xF, true);
}

// ---------------- main kernel: 256 blocks. role 0 = viterbi, role 1 = forward+num.
// 256 threads: j=tid>>1, h=tid&1 owns i-half [64h,64h+64). ----------------
__attribute__((amdgpu_flat_work_group_size(256, 256)))
__attribute__((amdgpu_waves_per_eu(1, 1)))
__global__ void crf_mainX(const float* __restrict__ logit,
                          const int* __restrict__ seq_lens,
                          const float* __restrict__ trans,
                          const float* __restrict__ startT,
                          const float* __restrict__ endT,
                          const int* __restrict__ target,
                          uint8_t* __restrict__ histG,
                          float* __restrict__ scr_logZ,
                          int* __restrict__ scr_last,
                          float* __restrict__ scr_num)
{
    extern __shared__ float smem[];
    float* transLDS = smem;                         // TT*TRP = 16512 floats
    float* vecLDS   = smem + 16512;                 // 2*VSTRIDE = 272
    float* ringLDS  = smem + 16512 + 272;           // 4
    float* redLDS   = smem + 16512 + 276;           // 8
    int*   redILDS  = (int*)(smem + 16512 + 284);   // 4
    float* sumLDS   = smem + 16512 + 288;           // 4

    const int bid = blockIdx.x;
    const int role = bid >> 7;
    const int b = bid & (BB - 1);
    const int tid = threadIdx.x;
    const int j = tid >> 1;
    const int h = tid & 1;
    const int ibase0 = h << 6;
    const int joff = j + ((j >= 64) ? (H1OFF - 64) : 0);  // padded offset of column j
    const int L = seq_lens[b];
    const size_t lbase = (size_t)b * (SS * TT);

    // stage transitions into padded LDS (stride TRP)
    for (int m = tid; m < TT * TT; m += 256)
        transLDS[(m >> 7) * TRP + (m & 127)] = trans[m];
    __syncthreads();

    // depth-3 logit prefetch registers
    float e1 = 0.f, e2 = 0.f, e3 = 0.f;
    if (L > 1) e1 = logit[lbase + TT + j];
    e2 = (L > 2) ? logit[lbase + 2 * (size_t)TT + j] : e1;
    e3 = (L > 3) ? logit[lbase + 3 * (size_t)TT + j] : e2;

    if (role == 0) {
        // =================== VITERBI ===================
        f32x4 tC[16];  // trans[i][j] for my i-half
#pragma unroll
        for (int c = 0; c < 16; ++c) {
            tC[c].x = transLDS[(ibase0 + c * 4 + 0) * TRP + j];
            tC[c].y = transLDS[(ibase0 + c * 4 + 1) * TRP + j];
            tC[c].z = transLDS[(ibase0 + c * 4 + 2) * TRP + j];
            tC[c].w = transLDS[(ibase0 + c * 4 + 3) * TRP + j];
            PIN(tC[c]);
        }
        const float a0 = startT[j] + logit[lbase + j];
        if (h == 0) vecLDS[joff] = a0;
        __syncthreads();

        for (int t = 1; t < L; ++t) {
            const int cur = (t - 1) & 1, nxt = t & 1;
            const float e = e1; e1 = e2; e2 = e3;
            const int tn = (t + 3 < L) ? (t + 3) : (L - 1);
            e3 = logit[lbase + (size_t)tn * TT + j];

            // pass 1: P_i = s_i + t_ij (packed adds; +e deferred — exact monotonicity)
            const f32x4* sq = (const f32x4*)(vecLDS + cur * VSTRIDE + h * H1OFF);
            float cm[8];
#pragma unroll
            for (int c = 0; c < 8; ++c) {
                f32x4 pa = sq[2 * c] + tC[2 * c];
                f32x4 pb = sq[2 * c + 1] + tC[2 * c + 1];
                float m01 = fmaxf(pa.x, pa.y), m23 = fmaxf(pa.z, pa.w);
                float m45 = fmaxf(pb.x, pb.y), m67 = fmaxf(pb.z, pb.w);
                cm[c] = fmaxf(fmaxf(m01, m23), fmaxf(m45, m67));
            }
            float M = fmaxf(fmaxf(fmaxf(cm[0], cm[1]), fmaxf(cm[2], cm[3])),
                            fmaxf(fmaxf(cm[4], cm[5]), fmaxf(cm[6], cm[7])));
            const float Mall = fmaxf(M, dpp_swap1_f(M));
            const float v = Mall + e;   // exact reference max value

            // first chunk (in my half) whose max round-equals v after +e
            int cwin = -1;
#pragma unroll
            for (int c = 7; c >= 0; --c) cwin = ((cm[c] + e) == v) ? c : cwin;

            int idx = 0x7fffffff;
            if (cwin >= 0) {
                const int basei = ibase0 + cwin * 8;
                const float* tr = transLDS + (size_t)basei * TRP + j;
                const f32x4* sr = (const f32x4*)(vecLDS + cur * VSTRIDE + h * H1OFF + cwin * 8);
                f32x4 ra = sr[0], rb = sr[1];
                float q0 = (ra.x + tr[0 * TRP]) + e;
                float q1 = (ra.y + tr[1 * TRP]) + e;
                float q2 = (ra.z + tr[2 * TRP]) + e;
                float q3 = (ra.w + tr[3 * TRP]) + e;
                float q4 = (rb.x + tr[4 * TRP]) + e;
                float q5 = (rb.y + tr[5 * TRP]) + e;
                float q6 = (rb.z + tr[6 * TRP]) + e;
                float q7 = (rb.w + tr[7 * TRP]) + e;
                idx = (q7 == v) ? basei + 7 : idx;
                idx = (q6 == v) ? basei + 6 : idx;
                idx = (q5 == v) ? basei + 5 : idx;
                idx = (q4 == v) ? basei + 4 : idx;
                idx = (q3 == v) ? basei + 3 : idx;
                idx = (q2 == v) ? basei + 2 : idx;
                idx = (q1 == v) ? basei + 1 : idx;
                idx = (q0 == v) ? basei + 0 : idx;
            }
            const int oidx = dpp_swap1_i(idx);
            idx = (oidx < idx) ? oidx : idx;  // first-index across halves

            if (h == 0) {
                vecLDS[nxt * VSTRIDE + joff] = v;
                histG[(size_t)b * (SS * TT) + (size_t)t * TT + j] = (uint8_t)idx;
            }
            BAR();
        }

        // ---- last_tag = argmax_j(score + end), first-index ----
        const int fin = (L - 1) & 1;
        if (tid < 128) {
            const int toff = tid + ((tid >= 64) ? (H1OFF - 64) : 0);
            float lv = vecLDS[fin * VSTRIDE + toff] + endT[tid];
            int li = tid;
#pragma unroll
            for (int off = 1; off < 64; off <<= 1) {
                float ov = __shfl_xor(lv, off);
                int oi = __shfl_xor(li, off);
                if (ov > lv || (ov == lv && oi < li)) { lv = ov; li = oi; }
            }
            if ((tid & 63) == 0) { redLDS[tid >> 6] = lv; redILDS[tid >> 6] = li; }
        }
        __syncthreads();
        if (tid == 0) {
            int lt = (redLDS[1] > redLDS[0] ||
                      (redLDS[1] == redLDS[0] && redILDS[1] < redILDS[0]))
                     ? redILDS[1] : redILDS[0];
            scr_last[b] = lt;
        }
        // ---- identity fill of hist rows [L, SS) ----
        uint8_t* hb = histG + (size_t)b * (SS * TT);
        const int colq = (tid & 7) * 16;
        const uint32_t w0 = 0x03020100u + 0x01010101u * (uint32_t)colq;
        const uint4 pat = make_uint4(w0, w0 + 0x04040404u, w0 + 0x08080808u, w0 + 0x0C0C0C0Cu);
        for (int t0 = L; t0 < SS; t0 += 32) {
            int t = t0 + (tid >> 3);
            if (t < SS) *(uint4*)(hb + (size_t)t * TT + colq) = pat;
        }
    } else {
        // =================== FORWARD (logZ) ===================
        f32x4 tE[16];  // exp(trans[i][j])
#pragma unroll
        for (int c = 0; c < 16; ++c) {
            tE[c].x = __expf(transLDS[(ibase0 + c * 4 + 0) * TRP + j]);
            tE[c].y = __expf(transLDS[(ibase0 + c * 4 + 1) * TRP + j]);
            tE[c].z = __expf(transLDS[(ibase0 + c * 4 + 2) * TRP + j]);
            tE[c].w = __expf(transLDS[(ibase0 + c * 4 + 3) * TRP + j]);
            PIN(tE[c]);
        }
        const float a0 = startT[j] + logit[lbase + j];
        const float R0 = startT[0] + logit[lbase + 0];  // alpha0[0], uniform
        float alpha = a0;
        if (h == 0) vecLDS[joff] = __expf(a0 - R0);
        if (tid < 4) ringLDS[tid] = R0;
        __syncthreads();

        for (int t = 1; t < L; ++t) {
            const int cur = (t - 1) & 1, nxt = t & 1;
            const float Rcons = ringLDS[(t - 3) & 3];  // shift used by aexp[cur]
            const float Rpub  = ringLDS[(t - 2) & 3];  // shift for publishing aexp[nxt]
            const float e = e1; e1 = e2; e2 = e3;
            const int tn = (t + 3 < L) ? (t + 3) : (L - 1);
            e3 = logit[lbase + (size_t)tn * TT + j];

            const f32x4* aq = (const f32x4*)(vecLDS + cur * VSTRIDE + h * H1OFF);
            f32x4 s4 = {0.f, 0.f, 0.f, 0.f};
            f32x4 s4b = {0.f, 0.f, 0.f, 0.f};
#pragma unroll
            for (int c = 0; c < 16; c += 2) {
                s4  = aq[c] * tE[c] + s4;       // v_pk_fma_f32
                s4b = aq[c + 1] * tE[c + 1] + s4b;
            }
            f32x4 st = s4 + s4b;
            float Ssum = (st.x + st.y) + (st.z + st.w);
            Ssum += dpp_swap1_f(Ssum);
            alpha = e + Rcons + __logf(Ssum);
            const float p = __expf(alpha - Rpub);
            if (h == 0) vecLDS[nxt * VSTRIDE + joff] = p;
            if (tid == 0) ringLDS[t & 3] = alpha;  // slot t&3: no reader this step
            BAR();
        }

        // ---- logZ epilogue (exact max) ----
        const float fval = alpha + endT[j];
        float tmx = fval;
#pragma unroll
        for (int off = 1; off < 64; off <<= 1) tmx = fmaxf(tmx, __shfl_xor(tmx, off));
        if ((tid & 63) == 0) redLDS[4 + (tid >> 6)] = tmx;
        __syncthreads();
        const float gm = fmaxf(fmaxf(redLDS[4], redLDS[5]), fmaxf(redLDS[6], redLDS[7]));
        float se = (h == 0) ? __expf(fval - gm) : 0.f;
#pragma unroll
        for (int off = 1; off < 64; off <<= 1) se += __shfl_xor(se, off);
        if ((tid & 63) == 0) sumLDS[tid >> 6] = se;
        __syncthreads();
        if (tid == 0)
            scr_logZ[b] = gm + __logf(sumLDS[0] + sumLDS[1] + sumLDS[2] + sumLDS[3]);
        __syncthreads();

        // ---- numerator (gold path score) ----
        float acc = 0.f;
        for (int t = tid; t < L; t += 256) {
            int tg = target[b * SS + t];
            acc += logit[((size_t)b * SS + t) * TT + tg];
            if (t >= 1) acc += trans[target[b * SS + t - 1] * TT + tg];
        }
#pragma unroll
        for (int off = 1; off < 64; off <<= 1) acc += __shfl_xor(acc, off);
        if ((tid & 63) == 0) sumLDS[tid >> 6] = acc;
        __syncthreads();
        if (tid == 0) {
            float tot = sumLDS[0] + sumLDS[1] + sumLDS[2] + sumLDS[3];
            tot += startT[target[b * SS]] + endT[target[b * SS + L - 1]];
            scr_num[b] = tot;
        }
    }
}

// ---------------- phase 2: per-segment parallel backtrace of all 128 end-tags ----------------
__global__ void crf_btseg(uint8_t* __restrict__ histG)
{
    const int c = blockIdx.x;    // segment 0..31
    const int b = blockIdx.y;    // batch
    const int tid = threadIdx.x; // 128
    __shared__ __align__(16) uint8_t hl[SEGK * TT];

    const int lo = (c == 0) ? 1 : c * SEGK;
    const int nr = (c == 0) ? 63 : 64;
    const uint8_t* src = histG + (size_t)b * (SS * TT) + (size_t)lo * TT;
    for (int k = tid; k < (nr * TT) / 16; k += 128)
        ((uint4*)hl)[k] = ((const uint4*)src)[k];
    __syncthreads();

    int tau = tid;
    uint32_t w[16];
#pragma unroll
    for (int q = 0; q < 16; ++q) w[q] = 0u;
    if (c == 0) {
#pragma unroll
        for (int r = 62; r >= 0; --r) {
            tau = hl[r * TT + tau];
            w[r >> 2] |= ((uint32_t)tau) << ((r & 3) * 8);
        }
    } else {
#pragma unroll
        for (int r = 63; r >= 0; --r) {
            tau = hl[r * TT + tau];
            w[r >> 2] |= ((uint32_t)tau) << ((r & 3) * 8);
        }
    }
    uint4* dst = (uint4*)(histG + (size_t)b * (SS * TT) + (size_t)c * 8192 + (size_t)tid * 64);
    dst[0] = make_uint4(w[0], w[1], w[2], w[3]);
    dst[1] = make_uint4(w[4], w[5], w[6], w[7]);
    dst[2] = make_uint4(w[8], w[9], w[10], w[11]);
    dst[3] = make_uint4(w[12], w[13], w[14], w[15]);
}

// ---------------- phase 3: serial chain over 32 segment maps per batch ----------------
__global__ void crf_btchain(const uint8_t* __restrict__ histG,
                            const int* __restrict__ scr_last,
                            int* __restrict__ scr_bt,
                            float* __restrict__ out_pred)
{
    const int b = threadIdx.x;
    if (b >= BB) return;
    int tau = scr_last[b];
    out_pred[(size_t)b * SS + (SS - 1)] = (float)tau;
    for (int c = NSEG - 1; c >= 0; --c) {
        scr_bt[b * NSEG + c] = tau;
        tau = histG[(size_t)b * (SS * TT) + (size_t)c * 8192 + (size_t)tau * 64];
    }
}

// ---------------- phase 4: parallel fill of pred from chosen paths ----------------
__global__ void crf_btfill(const uint8_t* __restrict__ histG,
                           const int* __restrict__ scr_bt,
                           float* __restrict__ out_pred)
{
    const int c = blockIdx.x;
    const int b = blockIdx.y;
    const int s = threadIdx.x;   // 64
    if (c == 0 && s > 62) return;
    const int js = scr_bt[b * NSEG + c];
    uint8_t v = histG[(size_t)b * (SS * TT) + (size_t)c * 8192 + (size_t)js * 64 + s];
    const int pos = (c == 0) ? s : (c * SEGK - 1 + s);
    out_pred[(size_t)b * SS + pos] = (float)v;
}

// ---------------- loss = mean(logZ - num) ----------------
__global__ void crf_loss(const float* __restrict__ scr_logZ, const float* __restrict__ scr_num,
                         float* __restrict__ out)
{
    const int tid = threadIdx.x; // 128
    __shared__ float p2[2];
    float v = (tid < BB) ? (scr_logZ[tid] - scr_num[tid]) : 0.0f;
#pragma unroll
    for (int off = 1; off < 64; off <<= 1) v += __shfl_xor(v, off);
    if ((tid & 63) == 0) p2[tid >> 6] = v;
    __syncthreads();
    if (tid == 0) out[0] = (p2[0] + p2[1]) / (float)BB;
}

// ---------------- log_probs: swap + log_softmax, one wave per row ----------------
__global__ void crf_logprobs(const float* __restrict__ logit,
                             const float* __restrict__ predF,
                             float* __restrict__ outLP)
{
    const int wid = threadIdx.x >> 6;
    const int lane = threadIdx.x & 63;
    const size_t row = (size_t)blockIdx.x * 4 + wid;
    const float2* rp = (const float2*)(logit + row * TT);
    float2 v = rp[lane];
    const int pred = (int)predF[row];

    float mv; int mi;
    if (v.y > v.x) { mv = v.y; mi = lane * 2 + 1; }
    else           { mv = v.x; mi = lane * 2; }
#pragma unroll
    for (int off = 1; off < 64; off <<= 1) {
        float ov = __shfl_xor(mv, off);
        int oi = __shfl_xor(mi, off);
        if (ov > mv || (ov == mv && oi < mi)) { mv = ov; mi = oi; }
    }
    float se = __expf(v.x - mv) + __expf(v.y - mv);
#pragma unroll
    for (int off = 1; off < 64; off <<= 1) se += __shfl_xor(se, off);
    const float lse = __logf(se);

    float px = __shfl(v.x, pred >> 1);
    float py = __shfl(v.y, pred >> 1);
    float vp = (pred & 1) ? py : px;

    float ox = (lane * 2 == pred) ? mv : ((lane * 2 == mi) ? vp : v.x);
    float oy = (lane * 2 + 1 == pred) ? mv : ((lane * 2 + 1 == mi) ? vp : v.y);
    float* op = outLP + row * TT + lane * 2;
    op[0] = (ox - mv) - lse;
    op[1] = (oy - mv) - lse;
}

extern "C" void kernel_launch(void* const* d_in, const int* in_sizes, int n_in,
                              void* d_out, int out_size, void* d_ws, size_t ws_size,
                              hipStream_t stream)
{
    const float* logit    = (const float*)d_in[0];
    const int*   target   = (const int*)d_in[1];
    const int*   seq_lens = (const int*)d_in[2];
    const float* trans    = (const float*)d_in[3];
    const float* startT   = (const float*)d_in[4];
    const float* endT     = (const float*)d_in[5];

    float* out      = (float*)d_out;
    float* out_pred = out + 1;
    float* outLP    = out + 1 + (size_t)BB * SS;                 // 262145
    uint8_t* histG  = (uint8_t*)(out + 262148);                  // 16B-aligned, 33.5MB
    float* scr      = out + ((size_t)1 + (size_t)BB * SS + (size_t)BB * SS * TT - 4480);
    float* scr_logZ = scr;                // 128
    float* scr_num  = scr + 128;          // 128
    int*   scr_last = (int*)(scr + 256);  // 128
    int*   scr_bt   = (int*)(scr + 384);  // 128*32

    const int dynLDS = (16512 + 272 + 4 + 8 + 4 + 4 + 8) * 4;  // ~67.2KB
    hipFuncSetAttribute((const void*)crf_mainX,
                        hipFuncAttributeMaxDynamicSharedMemorySize, dynLDS);

    crf_mainX<<<2 * BB, 256, dynLDS, stream>>>(logit, seq_lens, trans, startT, endT,
                                               target, histG, scr_logZ, scr_last, scr_num);
    crf_btseg<<<dim3(NSEG, BB), 128, 0, stream>>>(histG);
    crf_btchain<<<1, 128, 0, stream>>>(histG, scr_last, scr_bt, out_pred);
    crf_btfill<<<dim3(NSEG, BB), 64, 0, stream>>>(histG, scr_bt, out_pred);
    crf_loss<<<1, 128, 0, stream>>>(scr_logZ, scr_num, out);
    crf_logprobs<<<(BB * SS) / 4, 256, 0, stream>>>(logit, out_pred, outLP);
}